// Round 7
// baseline (26.201 us; speedup 1.0000x reference)
//
#include <hip/hip_runtime.h>

// WeightedBoxPool with exact spatial pruning.
//   out[b,j] = sum_t mask_weight[b,t,j] * [ max_{i beats j} fl(iou(i,j)) < thr[t] ]
//   beat = key_i > key_j, key = (score_bits<<32) | (0x7fffffff - idx)   (scores > 0)
// Pairs with inter==0 can never win the tournament (0 > nb*uni is false), and
// i overlaps j only if |x1_i - x1_j| < wmax. So: counting-sort boxes by x1 into
// 64 bins (deterministic, no atomics); each 8-j block scans only bins covering
// [x1lo - wmaxm, x1hi + wmaxm]. bin() is a monotone float chain evaluated
// identically in prep and main, so no overlapping pair is ever skipped.
// Tournament math identical to rounds 2-6 (absmax 0.0): division-free running
// max via cross-multiply, one IEEE f32 divide per (thread,j), shfl max-reduce.
// Ragged tail uses clamped DUPLICATE evals (duplicates can't change a max).

constexpr int NB   = 64;     // x1 bins per batch
constexpr int JG   = 8;      // j columns per main block
constexpr int NTHR = 256;    // threads per main block
constexpr int PTH  = 256;    // threads per prep block

struct BatchMeta { float xmin, inv_binw, wmaxm, pad; };

__global__ __launch_bounds__(PTH)
void wbp_prep(const float* __restrict__ box, const float* __restrict__ score,
              float* __restrict__ rec, int* __restrict__ binstart,
              BatchMeta* __restrict__ meta, int N)
{
    const int b    = blockIdx.x;
    const int tid  = threadIdx.x;
    const int lane = tid & 63;
    const int wave = tid >> 6;

    const float* __restrict__ bx1 = box + (size_t)(b * 4 + 0) * N;
    const float* __restrict__ by1 = box + (size_t)(b * 4 + 1) * N;
    const float* __restrict__ bx2 = box + (size_t)(b * 4 + 2) * N;
    const float* __restrict__ by2 = box + (size_t)(b * 4 + 3) * N;
    const float* __restrict__ sc  = score + (size_t)b * N;

    __shared__ unsigned short cnt[PTH][NB];   // 32 KB per-thread histograms
    __shared__ int   chtot[4][NB], chpref[4][NB];
    __shared__ int   bst[NB + 1];
    __shared__ float red[32];
    __shared__ float s_xmin, s_inv, s_wm;

    // pass A: xmin, xmax of x1; wmax of (x2-x1)
    float lx = 3e38f, hx = -3e38f, lw = 0.f;
    for (int i = tid; i < N; i += PTH) {
        const float x1 = bx1[i], x2 = bx2[i];
        lx = fminf(lx, x1); hx = fmaxf(hx, x1); lw = fmaxf(lw, x2 - x1);
    }
    #pragma unroll
    for (int m = 32; m >= 1; m >>= 1) {
        lx = fminf(lx, __shfl_xor(lx, m, 64));
        hx = fmaxf(hx, __shfl_xor(hx, m, 64));
        lw = fmaxf(lw, __shfl_xor(lw, m, 64));
    }
    if (lane == 0) { red[wave] = lx; red[8 + wave] = hx; red[16 + wave] = lw; }
    __syncthreads();
    if (tid == 0) {
        lx = fminf(fminf(red[0], red[1]), fminf(red[2], red[3]));
        hx = fmaxf(fmaxf(red[8], red[9]), fmaxf(red[10], red[11]));
        lw = fmaxf(fmaxf(red[16], red[17]), fmaxf(red[18], red[19]));
        const float binw = fmaxf((hx - lx) / (float)NB, 1e-6f);
        s_xmin = lx; s_inv = 1.0f / binw; s_wm = lw * 1.0001f + 1.0f;
        BatchMeta m; m.xmin = lx; m.inv_binw = s_inv; m.wmaxm = s_wm; m.pad = 0.f;
        meta[b] = m;
    }
    __syncthreads();
    const float xmin = s_xmin, inv = s_inv;

    // zero my histogram row (128 B, 8B-aligned)
    {
        unsigned long long* row = (unsigned long long*)cnt[tid];
        #pragma unroll
        for (int q = 0; q < NB / 4; ++q) row[q] = 0ull;
    }
    __syncthreads();

    // per-thread histogram over a CONTIGUOUS index range (deterministic order)
    const int IPT = (N + PTH - 1) / PTH;
    const int it0 = tid * IPT, it1 = min(N, it0 + IPT);
    for (int i = it0; i < it1; ++i) {
        int bin = (int)((bx1[i] - xmin) * inv);
        bin = max(0, min(NB - 1, bin));
        cnt[tid][bin]++;
    }
    __syncthreads();

    // within-chunk column scan: wave w scans its 64 threads, lane = bin
    {
        int run = 0;
        const int t0 = wave * 64;
        for (int t = 0; t < 64; ++t) {
            const int v = cnt[t0 + t][lane];
            cnt[t0 + t][lane] = (unsigned short)run;
            run += v;
        }
        chtot[wave][lane] = run;
    }
    __syncthreads();
    // cross-chunk prefixes + bin starts (wave 0; lane = bin)
    if (wave == 0) {
        const int c0 = chtot[0][lane], c1 = chtot[1][lane],
                  c2 = chtot[2][lane], c3 = chtot[3][lane];
        chpref[0][lane] = 0;
        chpref[1][lane] = c0;
        chpref[2][lane] = c0 + c1;
        chpref[3][lane] = c0 + c1 + c2;
        const int tot = c0 + c1 + c2 + c3;
        int x = tot;
        #pragma unroll
        for (int d = 1; d < 64; d <<= 1) {
            const int y = __shfl_up(x, d, 64);
            if (lane >= d) x += y;
        }
        const int pref = x - tot;       // exclusive
        bst[lane] = pref;
        binstart[b * (NB + 1) + lane] = pref;
        if (lane == 63) {
            bst[64] = pref + tot;
            binstart[b * (NB + 1) + 64] = pref + tot;
        }
    }
    __syncthreads();

    // deterministic scatter: packed 32B records
    for (int i = it0; i < it1; ++i) {
        const float x1 = bx1[i], y1 = by1[i], x2 = bx2[i], y2 = by2[i];
        const float s  = sc[i];
        int bin = (int)((x1 - xmin) * inv);
        bin = max(0, min(NB - 1, bin));
        const int local = cnt[tid][bin];
        cnt[tid][bin] = (unsigned short)(local + 1);
        const int pos = bst[bin] + chpref[wave][bin] + local;
        float* r = rec + ((size_t)b * N + pos) * 8;
        float4 r0 = make_float4(x1, y1, x2, y2);
        float4 r1;
        r1.x = (x2 - x1) * (y2 - y1);                      // ref-identical area expr
        ((unsigned int*)&r1)[1] = 0x7fffffffu - (unsigned int)i;   // key lo
        ((unsigned int*)&r1)[2] = __float_as_uint(s);              // key hi
        r1.w = 0.f;
        *(float4*)r = r0;
        *(float4*)(r + 4) = r1;
    }
}

__global__ __launch_bounds__(NTHR)
void wbp_main(const float* __restrict__ rec, const int* __restrict__ binstart,
              const BatchMeta* __restrict__ meta,
              const float* __restrict__ mw, const float* __restrict__ thr,
              float* __restrict__ out, int N, int T)
{
    const int b     = blockIdx.y;
    const int pbase = blockIdx.x * JG;
    const int tid   = threadIdx.x;
    const int lane  = tid & 63;
    const int wave  = tid >> 6;

    const float* __restrict__ rb = rec + (size_t)b * N * 8;
    const int* __restrict__ bstg = binstart + b * (NB + 1);
    const BatchMeta mt = meta[b];

    float jx1[JG], jy1[JG], jx2[JG], jy2[JG], ja[JG];
    unsigned long long jkey[JG];
    float x1lo = 3e38f, x1hi = -3e38f;
    #pragma unroll
    for (int u = 0; u < JG; ++u) {
        const int p  = pbase + u;
        const int pc = min(p, N - 1);
        const float* r = rb + (size_t)pc * 8;
        jx1[u] = r[0]; jy1[u] = r[1]; jx2[u] = r[2]; jy2[u] = r[3]; ja[u] = r[4];
        const unsigned int klo = ((const unsigned int*)r)[5];
        const unsigned int khi = ((const unsigned int*)r)[6];
        jkey[u] = (p < N) ? (((unsigned long long)khi << 32) | klo) : ~0ull;
        x1lo = fminf(x1lo, jx1[u]); x1hi = fmaxf(x1hi, jx1[u]);
    }
    // candidate window: bins covering [x1lo - wmaxm, x1hi + wmaxm]
    int lob = (int)((x1lo - mt.wmaxm - mt.xmin) * mt.inv_binw);
    lob = max(0, min(NB - 1, lob));
    int hib = (int)((x1hi + mt.wmaxm - mt.xmin) * mt.inv_binw);
    hib = max(0, min(NB - 1, hib));
    const int lo = bstg[lob];
    const int hi = bstg[hib + 1];

    float nb[JG], db[JG];
    #pragma unroll
    for (int u = 0; u < JG; ++u) { nb[u] = 0.f; db[u] = 1.f; }

    for (int base = lo; base < hi; base += NTHR) {
        const int ic = min(base + tid, hi - 1);     // duplicates are exact-harmless
        const float* rr = rb + (size_t)ic * 8;
        const float4 r0 = *(const float4*)rr;
        const float4 r1 = *(const float4*)(rr + 4);
        const unsigned long long ikey =
            ((unsigned long long)__float_as_uint(r1.z) << 32) | __float_as_uint(r1.y);
        const float ia = r1.x;
        #pragma unroll
        for (int u = 0; u < JG; ++u) {
            const float ltx = fmaxf(jx1[u], r0.x);
            const float lty = fmaxf(jy1[u], r0.y);
            const float rbx = fminf(jx2[u], r0.z);
            const float rby = fminf(jy2[u], r0.w);
            const float w   = fmaxf(rbx - ltx, 0.f);
            const float h   = fmaxf(rby - lty, 0.f);
            const float inter = w * h;
            const float uni   = (ja[u] + ia) - inter;
            const bool take = (ikey > jkey[u]) && (inter * db[u] > nb[u] * uni);
            if (take) { nb[u] = inter; db[u] = uni; }   // branchless cndmask pair
        }
    }

    // one IEEE divide per (thread,j); wave max-reduce; cross-wave via LDS
    __shared__ float pq[4][JG];
    #pragma unroll
    for (int u = 0; u < JG; ++u) {
        float q = (nb[u] > 0.f) ? (nb[u] / db[u]) : 0.f;
        #pragma unroll
        for (int m = 32; m >= 1; m >>= 1)
            q = fmaxf(q, __shfl_xor(q, m, 64));
        if (lane == 0) pq[wave][u] = q;
    }
    __syncthreads();

    if (tid < JG) {
        const int p = pbase + tid;
        if (p < N) {
            const float qm = fmaxf(fmaxf(pq[0][tid], pq[1][tid]),
                                   fmaxf(pq[2][tid], pq[3][tid]));
            const unsigned int klo = ((const unsigned int*)(rb + (size_t)p * 8))[5];
            const int oj = (int)(0x7fffffffu - klo);
            float acc = 0.f;
            for (int t = 0; t < T; ++t)
                if (qm < thr[t])                        // survived threshold t
                    acc += mw[(size_t)(b * T + t) * N + oj];
            out[(size_t)b * N + oj] = acc;
        }
    }
}

extern "C" void kernel_launch(void* const* d_in, const int* in_sizes, int n_in,
                              void* d_out, int out_size, void* d_ws, size_t ws_size,
                              hipStream_t stream)
{
    const float* mw  = (const float*)d_in[0];   // [B,T,N]
    const float* box = (const float*)d_in[1];   // [B,4,N]
    const float* sc  = (const float*)d_in[2];   // [B,1,N]
    const float* thr = (const float*)d_in[3];   // [T]
    float* out = (float*)d_out;                 // [B,1,N]

    const int BN = in_sizes[2];
    const int T  = in_sizes[3];
    const int B  = 4;                           // problem constant
    const int N  = BN / B;

    // workspace layout (all rewritten by prep every call)
    float*     rec      = (float*)d_ws;                                  // B*N*32 B
    int*       binstart = (int*)((char*)d_ws + (size_t)B * N * 32);      // B*(NB+1)*4
    BatchMeta* meta     = (BatchMeta*)((char*)binstart
                                       + (size_t)B * (NB + 1) * sizeof(int));

    wbp_prep<<<B, PTH, 0, stream>>>(box, sc, rec, binstart, meta, N);

    dim3 grid((N + JG - 1) / JG, B);
    wbp_main<<<grid, NTHR, 0, stream>>>(rec, binstart, meta, mw, thr, out, N, T);
}